// Round 1
// baseline (487.937 us; speedup 1.0000x reference)
//
#include <hip/hip_runtime.h>

// SectorAttentionV2 on MI355X (gfx950)
// Phases:
//   wt_kernel:    W[k][n] f32 -> Wt[n][k] bf16 (x3 weights)
//   bias_kernel:  position-bias MLP -> biasw[b][nh][p][ks][w] f32
//   gemm<0>:      Q = x@Wq+bq   -> Qw[b][u][nh][p][d][col] bf16 (LDS-transposed epilogue)
//   gemm<1>:      K/V = s@W+b   -> Kw/Vw[b][u][nh][ks][d][col] bf16 (row-permuted epilogue)
//   attn_kernel:  per-window 4x4 attention, lane = window column, d split across wave pairs

typedef unsigned short u16;
typedef unsigned int u32;
typedef __attribute__((ext_vector_type(8))) short bf16x8;
typedef __attribute__((ext_vector_type(4))) float f32x4;
typedef __attribute__((ext_vector_type(8))) unsigned short u16x8;
typedef __attribute__((ext_vector_type(2))) unsigned int u32x2;

__device__ __forceinline__ u16 f2b(float f) {
  u32 u = __float_as_uint(f);
  return (u16)((u + 0x7FFFu + ((u >> 16) & 1u)) >> 16);  // RNE
}
__device__ __forceinline__ float b2f(u16 v) { return __uint_as_float(((u32)v) << 16); }
__device__ __forceinline__ u32 packb(float lo, float hi) {
  return (u32)f2b(lo) | ((u32)f2b(hi) << 16);
}

// ---------------- weight transpose + cvt ----------------
__global__ __launch_bounds__(256) void wt_kernel(const float* __restrict__ Wq,
                                                 const float* __restrict__ Wk,
                                                 const float* __restrict__ Wv,
                                                 u16* __restrict__ Wt) {
  const float* W = (blockIdx.y == 0) ? Wq : (blockIdx.y == 1) ? Wk : Wv;
  int g = blockIdx.x * 256 + threadIdx.x;          // 0..262143
  int n = g >> 9, k = g & 511;
  Wt[(size_t)blockIdx.y * 262144 + g] = f2b(W[k * 512 + n]);
}

// ---------------- bias MLP ----------------
// biasw[((b*8+nh)*4+p)*4+ks][w]  (w in [0,8192))
__global__ __launch_bounds__(256) void bias_kernel(
    const float* __restrict__ xpos, const float* __restrict__ spos,
    const float* __restrict__ pw1, const float* __restrict__ pb1,
    const float* __restrict__ bng, const float* __restrict__ bnb,
    const float* __restrict__ bnm, const float* __restrict__ bnv,
    const float* __restrict__ pw2, const float* __restrict__ pb2,
    float* __restrict__ biasw) {
  int t = threadIdx.x;
  int wl = t & 63, p = t >> 6;
  int n = blockIdx.x * 64 + wl;         // window id, 0..16383
  int b = n >> 13, w = n & 8191;

  float Am[16], Bm[16], Cm[16];
#pragma unroll
  for (int m = 0; m < 16; ++m) {
    float sc = bng[m] * rsqrtf(bnv[m] + 1e-5f);
    Am[m] = pw1[2 * m] * sc;
    Bm[m] = pw1[2 * m + 1] * sc;
    Cm[m] = (pb1[m] - bnm[m]) * sc + bnb[m];
  }
  size_t xi = ((size_t)(b * 32768 + p * 8192 + w)) * 2;
  float xp0 = xpos[xi], xp1 = xpos[xi + 1];
#pragma unroll
  for (int ks = 0; ks < 4; ++ks) {
    size_t si = ((size_t)((b * 4 + ks) * 8192 + w)) * 2;
    float r0 = xp0 - spos[si];
    float r1 = xp1 - spos[si + 1];
    float o[8];
#pragma unroll
    for (int oo = 0; oo < 8; ++oo) o[oo] = pb2[oo];
#pragma unroll
    for (int m = 0; m < 16; ++m) {
      float h = fmaxf(Am[m] * r0 + Bm[m] * r1 + Cm[m], 0.f);
#pragma unroll
      for (int oo = 0; oo < 8; ++oo) o[oo] += pw2[oo * 16 + m] * h;
    }
#pragma unroll
    for (int oo = 0; oo < 8; ++oo)
      biasw[((size_t)(((b * 8 + oo) * 4 + p) * 4 + ks)) * 8192 + w] = o[oo];
  }
}

// ---------------- GEMM: Out = A(f32)[65536x512] @ W(bf16,pre-transposed Bt[n][k]) + bias ----------------
// MODE 0: Q epilogue (LDS transpose -> Qw[b][u][nh][p][d][col])
// MODE 1: K/V epilogue (row-permuted -> Kw[b][u][nh][ks][d][col])
template <int MODE>
__global__ __launch_bounds__(256, 2) void gemm_kernel(const float* __restrict__ A,
                                                      const u16* __restrict__ Bt,
                                                      const float* __restrict__ biasv,
                                                      u16* __restrict__ Out) {
  __shared__ u16 lds[128 * 72 + 128 * 64];  // Alds padded 72, Blds linear 64
  u16* Alds = lds;
  u16* Blds = lds + 128 * 72;

  const int t = threadIdx.x;
  const int mt = blockIdx.x * 128;
  const int nt = blockIdx.y * 128;
  const int lane = t & 63, wv = t >> 6;
  const int wm = (wv & 1) * 64, wn = (wv >> 1) * 64;
  const int fr = lane & 15, kg = lane >> 4;

  f32x4 acc[4][4];
#pragma unroll
  for (int i = 0; i < 4; ++i)
#pragma unroll
    for (int j = 0; j < 4; ++j) acc[i][j] = (f32x4){0.f, 0.f, 0.f, 0.f};

  for (int kt = 0; kt < 512; kt += 64) {
    // stage A: 128 rows x 64 k, f32 -> bf16
#pragma unroll
    for (int i = 0; i < 8; ++i) {
      int flat = i * 256 + t;
      int row = flat >> 4, c4 = flat & 15;
      const float4 v = *(const float4*)(A + (size_t)(mt + row) * 512 + kt + c4 * 4);
      u32x2 pk;
      pk.x = packb(v.x, v.y);
      pk.y = packb(v.z, v.w);
      *(u32x2*)&Alds[row * 72 + c4 * 4] = pk;
    }
    // stage B: 128 n-rows x 64 k bf16 via global_load_lds (linear LDS dest)
#pragma unroll
    for (int ii = 0; ii < 4; ++ii) {
      int inst = wv * 4 + ii;
      int row = inst * 8 + (lane >> 3);
      int seg = lane & 7;
      const u16* g = Bt + (size_t)(nt + row) * 512 + kt + seg * 8;
      __builtin_amdgcn_global_load_lds((const __attribute__((address_space(1))) void*)g,
                                       (__attribute__((address_space(3))) void*)&Blds[inst * 512],
                                       16, 0, 0);
    }
    __syncthreads();
#pragma unroll
    for (int kk = 0; kk < 64; kk += 32) {
      bf16x8 af[4], bf[4];
#pragma unroll
      for (int i = 0; i < 4; ++i)
        af[i] = *(const bf16x8*)&Alds[(wm + i * 16 + fr) * 72 + kk + kg * 8];
#pragma unroll
      for (int j = 0; j < 4; ++j)
        bf[j] = *(const bf16x8*)&Blds[(wn + j * 16 + fr) * 64 + kk + kg * 8];
#pragma unroll
      for (int i = 0; i < 4; ++i)
#pragma unroll
        for (int j = 0; j < 4; ++j)
          acc[i][j] = __builtin_amdgcn_mfma_f32_16x16x32_bf16(af[i], bf[j], acc[i][j], 0, 0, 0);
    }
    __syncthreads();
  }

  if (MODE == 1) {
    // K/V: row r -> (u=r&15, ks=(r>>4)&3, d=(r>>6)&63, nh=r>>12)
#pragma unroll
    for (int i = 0; i < 4; ++i) {
#pragma unroll
      for (int r = 0; r < 4; ++r) {
        int m = mt + wm + i * 16 + kg * 4 + r;
        int b = m >> 15, rr = m & 32767;
        int u = rr & 15, ks = (rr >> 4) & 3, d = (rr >> 6) & 63, nh = rr >> 12;
        size_t base = ((((size_t)(b * 16 + u) * 8 + nh) * 4 + ks) * 64 + d) * 512;
#pragma unroll
        for (int j = 0; j < 4; ++j) {
          int col = nt + wn + j * 16 + fr;
          Out[base + col] = f2b(acc[i][j][r] + biasv[col]);
        }
      }
    }
  } else {
    // Q: transpose tile via LDS, then coalesced 128B runs along col(=w)
    u16* Clds = lds;  // 128*136 = 17408 u16, fits exactly
#pragma unroll
    for (int i = 0; i < 4; ++i)
#pragma unroll
      for (int r = 0; r < 4; ++r) {
        int row = wm + i * 16 + kg * 4 + r;
#pragma unroll
        for (int j = 0; j < 4; ++j) {
          int cl = wn + j * 16 + fr;
          Clds[row * 136 + cl] = f2b(acc[i][j][r] + biasv[nt + cl]);
        }
      }
    __syncthreads();
    int cl = t >> 1, half = t & 1;
    int cg = nt + cl, nh = cg >> 6, d = cg & 63;
    int b = mt >> 15, l0 = mt & 32767;
    int p = l0 >> 13, w0 = l0 & 8191;
    int u = w0 >> 9, colw0 = w0 & 511;
    size_t obase =
        ((((size_t)(b * 16 + u) * 8 + nh) * 4 + p) * 64 + d) * 512 + colw0 + half * 64;
#pragma unroll
    for (int g = 0; g < 8; ++g) {
      u16x8 vv;
#pragma unroll
      for (int e = 0; e < 8; ++e) vv[e] = Clds[(half * 64 + g * 8 + e) * 136 + cl];
      *(u16x8*)(Out + obase + g * 8) = vv;
    }
  }
}

// ---------------- attention ----------------
// block: (b,u,colgroup64) x 2 heads; wave pair splits d in halves; lane = col
__global__ __launch_bounds__(256, 4) void attn_kernel(const u16* __restrict__ Qw,
                                                      const u16* __restrict__ Kw,
                                                      const u16* __restrict__ Vw,
                                                      const float* __restrict__ biasw,
                                                      float* __restrict__ out) {
  __shared__ float slds[4 * 16 * 64];  // per-wave partial scores
  const int t = threadIdx.x, lane = t & 63, wv = t >> 6;
  const int blk = blockIdx.x;
  const int nhp = blk & 3, cg = (blk >> 2) & 7, u = (blk >> 5) & 15, b = blk >> 9;
  const int nh = nhp * 2 + (wv >> 1), dh = wv & 1;
  const int col = cg * 64 + lane;
  const int w = u * 512 + col;

  const size_t base0 = ((((size_t)(b * 16 + u) * 8 + nh) * 4) * 64 + dh * 32) * 512 + col;

  float sc[4][4];
#pragma unroll
  for (int p = 0; p < 4; ++p)
#pragma unroll
    for (int k = 0; k < 4; ++k) sc[p][k] = 0.f;

  {
    const u16* qp = Qw + base0;
    const u16* kp = Kw + base0;
#pragma unroll 4
    for (int dd = 0; dd < 32; ++dd) {
      int o = dd * 512;
      float q0 = b2f(qp[o]);
      float q1 = b2f(qp[o + 32768]);
      float q2 = b2f(qp[o + 65536]);
      float q3 = b2f(qp[o + 98304]);
      float k0 = b2f(kp[o]);
      float k1 = b2f(kp[o + 32768]);
      float k2 = b2f(kp[o + 65536]);
      float k3 = b2f(kp[o + 98304]);
      sc[0][0] += q0 * k0; sc[0][1] += q0 * k1; sc[0][2] += q0 * k2; sc[0][3] += q0 * k3;
      sc[1][0] += q1 * k0; sc[1][1] += q1 * k1; sc[1][2] += q1 * k2; sc[1][3] += q1 * k3;
      sc[2][0] += q2 * k0; sc[2][1] += q2 * k1; sc[2][2] += q2 * k2; sc[2][3] += q2 * k3;
      sc[3][0] += q3 * k0; sc[3][1] += q3 * k1; sc[3][2] += q3 * k2; sc[3][3] += q3 * k3;
    }
  }

  // exchange partial d-half sums with partner wave (wv^1, same head)
#pragma unroll
  for (int pk = 0; pk < 16; ++pk)
    slds[(wv * 16 + pk) * 64 + lane] = sc[pk >> 2][pk & 3];
  __syncthreads();

  float a[4][4];
  const size_t bbase = ((size_t)(b * 8 + nh) * 16) * 8192 + w;
#pragma unroll
  for (int p = 0; p < 4; ++p) {
    float s0 = sc[p][0] + slds[((wv ^ 1) * 16 + p * 4 + 0) * 64 + lane];
    float s1 = sc[p][1] + slds[((wv ^ 1) * 16 + p * 4 + 1) * 64 + lane];
    float s2 = sc[p][2] + slds[((wv ^ 1) * 16 + p * 4 + 2) * 64 + lane];
    float s3 = sc[p][3] + slds[((wv ^ 1) * 16 + p * 4 + 3) * 64 + lane];
    s0 = s0 * 0.125f + biasw[bbase + (size_t)(p * 4 + 0) * 8192];
    s1 = s1 * 0.125f + biasw[bbase + (size_t)(p * 4 + 1) * 8192];
    s2 = s2 * 0.125f + biasw[bbase + (size_t)(p * 4 + 2) * 8192];
    s3 = s3 * 0.125f + biasw[bbase + (size_t)(p * 4 + 3) * 8192];
    float mx = fmaxf(fmaxf(s0, s1), fmaxf(s2, s3));
    float e0 = __expf(s0 - mx), e1 = __expf(s1 - mx), e2 = __expf(s2 - mx), e3 = __expf(s3 - mx);
    float inv = 1.f / (e0 + e1 + e2 + e3);
    a[p][0] = e0 * inv; a[p][1] = e1 * inv; a[p][2] = e2 * inv; a[p][3] = e3 * inv;
  }

  // PV + store (per-lane rows are contiguous 128B in d -> float4 stores)
  const u16* vp = Vw + base0;
  const size_t obase = ((size_t)(b * 32768 + w)) * 512 + nh * 64 + dh * 32;
#pragma unroll
  for (int g = 0; g < 8; ++g) {
    float vd[4][4];
#pragma unroll
    for (int e = 0; e < 4; ++e) {
      int o = (g * 4 + e) * 512;
      vd[0][e] = b2f(vp[o]);
      vd[1][e] = b2f(vp[o + 32768]);
      vd[2][e] = b2f(vp[o + 65536]);
      vd[3][e] = b2f(vp[o + 98304]);
    }
#pragma unroll
    for (int p = 0; p < 4; ++p) {
      float4 ov;
      ov.x = a[p][0] * vd[0][0] + a[p][1] * vd[1][0] + a[p][2] * vd[2][0] + a[p][3] * vd[3][0];
      ov.y = a[p][0] * vd[0][1] + a[p][1] * vd[1][1] + a[p][2] * vd[2][1] + a[p][3] * vd[3][1];
      ov.z = a[p][0] * vd[0][2] + a[p][1] * vd[1][2] + a[p][2] * vd[2][2] + a[p][3] * vd[3][2];
      ov.w = a[p][0] * vd[0][3] + a[p][1] * vd[1][3] + a[p][2] * vd[2][3] + a[p][3] * vd[3][3];
      *(float4*)(out + obase + (size_t)p * 4194304 + g * 4) = ov;
    }
  }
}

// ---------------- launch ----------------
extern "C" void kernel_launch(void* const* d_in, const int* in_sizes, int n_in,
                              void* d_out, int out_size, void* d_ws, size_t ws_size,
                              hipStream_t stream) {
  (void)in_sizes; (void)n_in; (void)out_size; (void)ws_size;
  const float* s     = (const float*)d_in[0];
  const float* x     = (const float*)d_in[1];
  const float* s_pos = (const float*)d_in[2];
  const float* x_pos = (const float*)d_in[3];
  const float* Wq = (const float*)d_in[4];  const float* bq = (const float*)d_in[5];
  const float* Wk = (const float*)d_in[6];  const float* bk = (const float*)d_in[7];
  const float* Wv = (const float*)d_in[8];  const float* bv = (const float*)d_in[9];
  const float* pw1 = (const float*)d_in[10]; const float* pb1 = (const float*)d_in[11];
  const float* bng = (const float*)d_in[12]; const float* bnb = (const float*)d_in[13];
  const float* bnm = (const float*)d_in[14]; const float* bnv = (const float*)d_in[15];
  const float* pw2 = (const float*)d_in[16]; const float* pb2 = (const float*)d_in[17];
  float* out = (float*)d_out;

  char* ws = (char*)d_ws;
  u16* Qw = (u16*)ws;                           // 67,108,864 B
  u16* Kw = (u16*)(ws + 67108864);              // 67,108,864 B
  u16* Vw = (u16*)(ws + 134217728);             // 67,108,864 B
  float* biasw = (float*)(ws + 201326592);      //  8,388,608 B
  u16* Wt = (u16*)(ws + 209715200);             //  1,572,864 B  (3 x 512x512 bf16)

  wt_kernel<<<dim3(1024, 3), 256, 0, stream>>>(Wq, Wk, Wv, Wt);
  bias_kernel<<<dim3(256), 256, 0, stream>>>(x_pos, s_pos, pw1, pb1, bng, bnb, bnm, bnv,
                                             pw2, pb2, biasw);
  gemm_kernel<0><<<dim3(512, 4), 256, 0, stream>>>(x, Wt, bq, Qw);
  gemm_kernel<1><<<dim3(512, 4), 256, 0, stream>>>(s, Wt + 262144, bk, Kw);
  gemm_kernel<1><<<dim3(512, 4), 256, 0, stream>>>(s, Wt + 524288, bv, Vw);
  attn_kernel<<<dim3(1024), 256, 0, stream>>>(Qw, Kw, Vw, biasw, out);
}